// Round 6
// baseline (355.871 us; speedup 1.0000x reference)
//
#include <hip/hip_runtime.h>
#include <math.h>

// Problem constants
#define NB 64    // N batch
#define LL 128   // L
#define DV 16
#define DD 256   // D
#define HH 8     // heads
#define DK 32    // D/H
#define FF 1024
#define LC 3
#define KNN 6
#define MS 16

typedef __attribute__((ext_vector_type(8))) short s16x8;   // 8 bf16 (4 VGPR)
typedef __attribute__((ext_vector_type(4))) float f32x4;   // MFMA acc

static __device__ inline unsigned short f2b(float x) {
    union { float f; unsigned int u; } v; v.f = x;
    unsigned int r = (v.u + 0x7FFFu + ((v.u >> 16) & 1u)) >> 16;
    return (unsigned short)r;
}

// ---------------------------------------------------------------------------
// Input projection: h = veh @ Wp + bp ; writes f32 h and bf16 mirror hb
// ---------------------------------------------------------------------------
__global__ __launch_bounds__(256)
void proj_kernel(const float* __restrict__ veh, const float* __restrict__ Wp,
                 const float* __restrict__ bp, float* __restrict__ h,
                 unsigned short* __restrict__ hb) {
    int m = blockIdx.x;
    int j = threadIdx.x;
    __shared__ float vrow[DV];
    if (j < DV) vrow[j] = veh[m * DV + j];
    __syncthreads();
    float acc = bp[j];
#pragma unroll
    for (int t = 0; t < DV; ++t) acc += vrow[t] * Wp[t * DD + j];
    h[(size_t)m * DD + j] = acc;
    hb[(size_t)m * DD + j] = f2b(acc);
}

// ---------------------------------------------------------------------------
// Pack cost = edges[...,0] into contiguous (N,L,L)
// ---------------------------------------------------------------------------
__global__ __launch_bounds__(256)
void pack_cost(const float* __restrict__ edges, float* __restrict__ cost) {
    int t = blockIdx.x * 256 + threadIdx.x;
    const float4* e4 = reinterpret_cast<const float4*>(edges) + (size_t)t * 4;
    float4 a = e4[0], b = e4[1], c = e4[2], d = e4[3];
    reinterpret_cast<float4*>(cost)[t] = make_float4(a.x, b.x, c.x, d.x);
}

// ---------------------------------------------------------------------------
// kNN mask as u64 bitmap: mb64[row][0]=cols 0..63, [1]=cols 64..127; bit=1
// means BLOCKED. Wave-parallel min-with-index, ballot to build the bitmap.
// ---------------------------------------------------------------------------
__global__ __launch_bounds__(256)
void knn2(const float* __restrict__ cost, unsigned long long* __restrict__ mb64) {
    int row = blockIdx.x * 4 + (threadIdx.x >> 6);
    int lane = threadIdx.x & 63;
    const float* cr = cost + (size_t)row * LL;
    float v0 = cr[lane], v1 = cr[lane + 64];
    int i0 = lane, i1 = lane + 64;
    bool s0 = false, s1 = false;
#pragma unroll
    for (int k = 0; k < KNN; ++k) {
        float v; int i;
        if (v1 < v0) { v = v1; i = i1; } else { v = v0; i = i0; }
#pragma unroll
        for (int o = 1; o < 64; o <<= 1) {
            float ov = __shfl_xor(v, o);
            int oi = __shfl_xor(i, o);
            if (ov < v || (ov == v && oi < i)) { v = ov; i = oi; }
        }
        if (i == i0) { s0 = true; v0 = 3.4e38f; }
        if (i == i1) { s1 = true; v1 = 3.4e38f; }
    }
    unsigned long long b0 = __ballot(s0);
    unsigned long long b1 = __ballot(s1);
    if (lane == 0) {
        mb64[(size_t)row * 2 + 0] = ~b0;
        mb64[(size_t)row * 2 + 1] = ~b1;
    }
}

// ---------------------------------------------------------------------------
// Transpose + bf16-cast weights: in (LC, K, N) f32 -> out (LC, N, K) bf16
// ---------------------------------------------------------------------------
__global__ __launch_bounds__(256)
void transposeW(const float* __restrict__ in, unsigned short* __restrict__ out,
                int K, int N, long in_lstride, long out_lstride) {
    int l = blockIdx.z;
    const float* inp = in + (size_t)l * in_lstride;
    unsigned short* outp = out + (size_t)l * out_lstride;
    int tx = threadIdx.x & 31, ty = threadIdx.x >> 5;
    int k0 = blockIdx.y * 32, n0 = blockIdx.x * 32;
    __shared__ float T[32][33];
#pragma unroll
    for (int r = 0; r < 4; ++r)
        T[ty + r * 8][tx] = inp[(size_t)(k0 + ty + r * 8) * N + n0 + tx];
    __syncthreads();
#pragma unroll
    for (int r = 0; r < 4; ++r)
        outp[(size_t)(n0 + ty + r * 8) * K + k0 + tx] = f2b(T[tx][ty + r * 8]);
}

// ---------------------------------------------------------------------------
// MFMA GEMM, 128x64 tile: C = A(MxK bf16) @ Bt^T (Bt NxK bf16) + bias
// 256 threads = 4 waves; wave w = rows w*32..w*32+31, all 64 cols.
// MODE 0: f32 out. MODE 1: bf16+relu.
// ---------------------------------------------------------------------------
template <int MODE>
__global__ __launch_bounds__(256)
void mmfma128(const unsigned short* __restrict__ A, const unsigned short* __restrict__ Bt,
              const float* __restrict__ bias, void* __restrict__ Cout,
              int M, int N, int K) {
    __shared__ unsigned short As[128 * 40];
    __shared__ unsigned short Bs[64 * 40];
    int tid = threadIdx.x;
    int w = tid >> 6, l = tid & 63;
    int lr = l & 15, lg = l >> 4;
    int m0 = blockIdx.y * 128, n0 = blockIdx.x * 64;
    int row = tid >> 2, seg = tid & 3;

    f32x4 acc[2][4];
#pragma unroll
    for (int i = 0; i < 2; ++i)
#pragma unroll
        for (int j = 0; j < 4; ++j) acc[i][j] = (f32x4)(0.f);

    for (int k0 = 0; k0 < K; k0 += 32) {
        int4 a0 = *reinterpret_cast<const int4*>(A  + (size_t)(m0 + row) * K + k0 + seg * 8);
        int4 a1 = *reinterpret_cast<const int4*>(A  + (size_t)(m0 + 64 + row) * K + k0 + seg * 8);
        int4 bv = *reinterpret_cast<const int4*>(Bt + (size_t)(n0 + row) * K + k0 + seg * 8);
        __syncthreads();
        *reinterpret_cast<int4*>(As + row * 40 + seg * 8) = a0;
        *reinterpret_cast<int4*>(As + (64 + row) * 40 + seg * 8) = a1;
        *reinterpret_cast<int4*>(Bs + row * 40 + seg * 8) = bv;
        __syncthreads();
        s16x8 af[2], bf[4];
#pragma unroll
        for (int i = 0; i < 2; ++i)
            af[i] = *reinterpret_cast<const s16x8*>(As + (w * 32 + i * 16 + lr) * 40 + lg * 8);
#pragma unroll
        for (int j = 0; j < 4; ++j)
            bf[j] = *reinterpret_cast<const s16x8*>(Bs + (j * 16 + lr) * 40 + lg * 8);
#pragma unroll
        for (int i = 0; i < 2; ++i)
#pragma unroll
            for (int j = 0; j < 4; ++j)
                acc[i][j] = __builtin_amdgcn_mfma_f32_16x16x32_bf16(af[i], bf[j], acc[i][j], 0, 0, 0);
    }

#pragma unroll
    for (int i = 0; i < 2; ++i)
#pragma unroll
        for (int j = 0; j < 4; ++j) {
            int col = n0 + j * 16 + lr;
            float bv = bias[col];
#pragma unroll
            for (int q = 0; q < 4; ++q) {
                int r = m0 + w * 32 + i * 16 + lg * 4 + q;
                float v = acc[i][j][q] + bv;
                if (MODE == 1) {
                    v = fmaxf(v, 0.f);
                    ((unsigned short*)Cout)[(size_t)r * N + col] = f2b(v);
                } else {
                    ((float*)Cout)[(size_t)r * N + col] = v;
                }
            }
        }
}

// ---------------------------------------------------------------------------
// MFMA GEMM, 128x128 tile (for FF1): bf16 out + bias + relu.
// 4 waves 2x2; wave owns 64x64 = 4x4 frags = 16 MFMA/K-step.
// ---------------------------------------------------------------------------
__global__ __launch_bounds__(256)
void mmfma256relu(const unsigned short* __restrict__ A, const unsigned short* __restrict__ Bt,
                  const float* __restrict__ bias, unsigned short* __restrict__ Cout,
                  int M, int N, int K) {
    __shared__ unsigned short As[128 * 40];
    __shared__ unsigned short Bs[128 * 40];
    int tid = threadIdx.x;
    int w = tid >> 6, l = tid & 63;
    int wr = w >> 1, wc = w & 1;
    int lr = l & 15, lg = l >> 4;
    int m0 = blockIdx.y * 128, n0 = blockIdx.x * 128;

    f32x4 acc[4][4];
#pragma unroll
    for (int i = 0; i < 4; ++i)
#pragma unroll
        for (int j = 0; j < 4; ++j) acc[i][j] = (f32x4)(0.f);

    for (int k0 = 0; k0 < K; k0 += 32) {
        int4 a[2], b[2];
#pragma unroll
        for (int it = 0; it < 2; ++it) {
            int task = tid + it * 256;
            int row = task >> 2, seg = task & 3;
            a[it] = *reinterpret_cast<const int4*>(A  + (size_t)(m0 + row) * K + k0 + seg * 8);
            b[it] = *reinterpret_cast<const int4*>(Bt + (size_t)(n0 + row) * K + k0 + seg * 8);
        }
        __syncthreads();
#pragma unroll
        for (int it = 0; it < 2; ++it) {
            int task = tid + it * 256;
            int row = task >> 2, seg = task & 3;
            *reinterpret_cast<int4*>(As + row * 40 + seg * 8) = a[it];
            *reinterpret_cast<int4*>(Bs + row * 40 + seg * 8) = b[it];
        }
        __syncthreads();
        s16x8 af[4], bf[4];
#pragma unroll
        for (int i = 0; i < 4; ++i)
            af[i] = *reinterpret_cast<const s16x8*>(As + (wr * 64 + i * 16 + lr) * 40 + lg * 8);
#pragma unroll
        for (int j = 0; j < 4; ++j)
            bf[j] = *reinterpret_cast<const s16x8*>(Bs + (wc * 64 + j * 16 + lr) * 40 + lg * 8);
#pragma unroll
        for (int i = 0; i < 4; ++i)
#pragma unroll
            for (int j = 0; j < 4; ++j)
                acc[i][j] = __builtin_amdgcn_mfma_f32_16x16x32_bf16(af[i], bf[j], acc[i][j], 0, 0, 0);
    }

#pragma unroll
    for (int i = 0; i < 4; ++i)
#pragma unroll
        for (int j = 0; j < 4; ++j) {
            int col = n0 + wc * 64 + j * 16 + lr;
            float bv = bias[col];
#pragma unroll
            for (int q = 0; q < 4; ++q) {
                int r = m0 + wr * 64 + i * 16 + lg * 4 + q;
                float v = fmaxf(acc[i][j][q] + bv, 0.f);
                Cout[(size_t)r * N + col] = f2b(v);
            }
        }
}

// ---------------------------------------------------------------------------
// Unified QKV GEMM: A(8192x256) @ WtQKV^T (768x256) ; 128x64 tiles.
// n0 in [0,768): s = n0>>8 selects q/k/v (block-uniform). Outputs bf16:
//   q,k head-major [bh][128][32]; v transposed [bh][32][128]
// ---------------------------------------------------------------------------
__global__ __launch_bounds__(256)
void qkv3(const unsigned short* __restrict__ A, const unsigned short* __restrict__ Bt,
          unsigned short* __restrict__ qb, unsigned short* __restrict__ kb,
          unsigned short* __restrict__ vtb) {
    const int K = DD;
    __shared__ unsigned short As[128 * 40];
    __shared__ unsigned short Bs[64 * 40];
    int tid = threadIdx.x;
    int w = tid >> 6, l = tid & 63;
    int lr = l & 15, lg = l >> 4;
    int m0 = blockIdx.y * 128, n0 = blockIdx.x * 64;
    int row = tid >> 2, seg = tid & 3;

    f32x4 acc[2][4];
#pragma unroll
    for (int i = 0; i < 2; ++i)
#pragma unroll
        for (int j = 0; j < 4; ++j) acc[i][j] = (f32x4)(0.f);

    for (int k0 = 0; k0 < K; k0 += 32) {
        int4 a0 = *reinterpret_cast<const int4*>(A  + (size_t)(m0 + row) * K + k0 + seg * 8);
        int4 a1 = *reinterpret_cast<const int4*>(A  + (size_t)(m0 + 64 + row) * K + k0 + seg * 8);
        int4 bv = *reinterpret_cast<const int4*>(Bt + (size_t)(n0 + row) * K + k0 + seg * 8);
        __syncthreads();
        *reinterpret_cast<int4*>(As + row * 40 + seg * 8) = a0;
        *reinterpret_cast<int4*>(As + (64 + row) * 40 + seg * 8) = a1;
        *reinterpret_cast<int4*>(Bs + row * 40 + seg * 8) = bv;
        __syncthreads();
        s16x8 af[2], bf[4];
#pragma unroll
        for (int i = 0; i < 2; ++i)
            af[i] = *reinterpret_cast<const s16x8*>(As + (w * 32 + i * 16 + lr) * 40 + lg * 8);
#pragma unroll
        for (int j = 0; j < 4; ++j)
            bf[j] = *reinterpret_cast<const s16x8*>(Bs + (j * 16 + lr) * 40 + lg * 8);
#pragma unroll
        for (int i = 0; i < 2; ++i)
#pragma unroll
            for (int j = 0; j < 4; ++j)
                acc[i][j] = __builtin_amdgcn_mfma_f32_16x16x32_bf16(af[i], bf[j], acc[i][j], 0, 0, 0);
    }

    int s = n0 >> 8;          // 0=q, 1=k, 2=v  (block-uniform)
    int nn = blockIdx.y >> 0; // m0 = nn*128 since M-tile == LL
#pragma unroll
    for (int i = 0; i < 2; ++i)
#pragma unroll
        for (int j = 0; j < 4; ++j) {
            int cc = (n0 & 255) + j * 16 + lr;
            int hh = cc >> 5, dk = cc & 31;
            int rl = w * 32 + i * 16 + lg * 4;     // row in [0,128)
            if (s == 2) {
                ushort4 u;
                u.x = f2b(acc[i][j][0]); u.y = f2b(acc[i][j][1]);
                u.z = f2b(acc[i][j][2]); u.w = f2b(acc[i][j][3]);
                *reinterpret_cast<ushort4*>(
                    vtb + ((size_t)(nn * HH + hh) * DK + dk) * LL + rl) = u;
            } else {
                unsigned short* dst = s ? kb : qb;
                size_t ho = ((size_t)(nn * HH + hh) * LL + rl) * DK + dk;
#pragma unroll
                for (int q = 0; q < 4; ++q)
                    dst[ho + (size_t)q * DK] = f2b(acc[i][j][q]);
            }
        }
}

// ---------------------------------------------------------------------------
// Fused attention v5: barrier-free. grid = N*H*4 blocks of 128 thr (2 waves).
// Each wave owns 16 q-rows, fully independent: reads K/V fragments directly
// from global (L2-resident, 8KB each per bh). LDS = wave-private P only.
// ---------------------------------------------------------------------------
__global__ __launch_bounds__(128)
void fattn5(const unsigned short* __restrict__ qb, const unsigned short* __restrict__ kb,
            const unsigned short* __restrict__ vtb, const float* __restrict__ cost,
            const unsigned long long* __restrict__ mb64,
            const float* __restrict__ m1w, const float* __restrict__ m1b,
            const float* __restrict__ m2w, const float* __restrict__ m2b,
            unsigned short* __restrict__ attc) {
    int blk = blockIdx.x;
    int bh = blk >> 2, quarter = blk & 3;
    int n = bh >> 3, hh = bh & 7;
    int tid = threadIdx.x;
    int w = tid >> 6, l = tid & 63;
    int lr = l & 15, lg = l >> 4;

    __shared__ unsigned short Ps[2 * 16 * 136];   // per-wave P (unnormalized)
    unsigned short* Pw = Ps + w * (16 * 136);

    int r0 = quarter * 32 + w * 16;
    const unsigned short* kg = kb + (size_t)bh * LL * DK;
    const unsigned short* vg = vtb + (size_t)bh * DK * LL;

    // QK^T: A-frag from global Q, 8 B-frags from global K (L2)
    s16x8 aq = *reinterpret_cast<const s16x8*>(
        qb + ((size_t)bh * LL + r0 + lr) * DK + lg * 8);
    f32x4 acc[8];
#pragma unroll
    for (int j = 0; j < 8; ++j) acc[j] = (f32x4)(0.f);
#pragma unroll
    for (int j = 0; j < 8; ++j) {
        s16x8 bk = *reinterpret_cast<const s16x8*>(kg + (j * 16 + lr) * DK + lg * 8);
        acc[j] = __builtin_amdgcn_mfma_f32_16x16x32_bf16(aq, bk, acc[j], 0, 0, 0);
    }

    // cost + mask for this lane's 32 (row,col) elements
    int rbase = r0 + lg * 4;
    const float* crow = cost + (size_t)n * LL * LL;
    float pc[8][4];
#pragma unroll
    for (int j = 0; j < 8; ++j)
#pragma unroll
        for (int q = 0; q < 4; ++q)
            pc[j][q] = crow[(rbase + q) * LL + j * 16 + lr];
    ulonglong2 mrow[4];
    {
        const ulonglong2* mbp = reinterpret_cast<const ulonglong2*>(
            mb64 + (size_t)(n * LL + rbase) * 2);
#pragma unroll
        for (int q = 0; q < 4; ++q) mrow[q] = mbp[q];
    }

    // mixer MLP
    const float scale = 0.17677669529663687f;  // 1/sqrt(32)
    const float* w0g = m1w + (hh * 2 + 0) * MS;
    const float* w1g = m1w + (hh * 2 + 1) * MS;
    const float* b1g = m1b + hh * MS;
    const float* w2g = m2w + hh * MS;
    float b2v = m2b[hh];
    float sreg[8][4];
#pragma unroll
    for (int j = 0; j < 8; ++j)
#pragma unroll
        for (int q = 0; q < 4; ++q) sreg[j][q] = b2v;
#pragma unroll
    for (int m = 0; m < MS; ++m) {
        float w0 = w0g[m] * scale;
        float w1 = w1g[m], bb = b1g[m], w2 = w2g[m];
#pragma unroll
        for (int j = 0; j < 8; ++j)
#pragma unroll
            for (int q = 0; q < 4; ++q)
                sreg[j][q] += fmaxf(acc[j][q] * w0 + pc[j][q] * w1 + bb, 0.f) * w2;
    }
#pragma unroll
    for (int q = 0; q < 4; ++q) {
        unsigned long long lo = mrow[q].x >> lr, hi = mrow[q].y >> lr;
#pragma unroll
        for (int j = 0; j < 8; ++j) {
            unsigned long long mh = (j < 4) ? lo : hi;
            if ((mh >> ((j & 3) * 16)) & 1ull) sreg[j][q] = -1e9f;
        }
    }

    // softmax per row (16-lane shfl), P unnormalized -> LDS
    float invq[4];
#pragma unroll
    for (int q = 0; q < 4; ++q) {
        float mx = sreg[0][q];
#pragma unroll
        for (int j = 1; j < 8; ++j) mx = fmaxf(mx, sreg[j][q]);
#pragma unroll
        for (int o = 1; o < 16; o <<= 1) mx = fmaxf(mx, __shfl_xor(mx, o));
        float e[8], sum = 0.f;
#pragma unroll
        for (int j = 0; j < 8; ++j) { e[j] = __expf(sreg[j][q] - mx); sum += e[j]; }
#pragma unroll
        for (int o = 1; o < 16; o <<= 1) sum += __shfl_xor(sum, o);
        invq[q] = 1.f / sum;
        int prow = (lg * 4 + q) * 136;
#pragma unroll
        for (int j = 0; j < 8; ++j)
            Pw[prow + j * 16 + lr] = f2b(e[j]);
    }

    // PV: A-frags from wave-private LDS P, B-frags from global V^T (L2)
    f32x4 av[2];
    av[0] = (f32x4)(0.f); av[1] = (f32x4)(0.f);
#pragma unroll
    for (int ks = 0; ks < 4; ++ks) {
        s16x8 ap = *reinterpret_cast<const s16x8*>(&Pw[lr * 136 + ks * 32 + lg * 8]);
#pragma unroll
        for (int jn = 0; jn < 2; ++jn) {
            s16x8 bv = *reinterpret_cast<const s16x8*>(vg + (jn * 16 + lr) * LL + ks * 32 + lg * 8);
            av[jn] = __builtin_amdgcn_mfma_f32_16x16x32_bf16(ap, bv, av[jn], 0, 0, 0);
        }
    }
#pragma unroll
    for (int jn = 0; jn < 2; ++jn) {
        int d = jn * 16 + lr;
#pragma unroll
        for (int q = 0; q < 4; ++q) {
            int r = r0 + lg * 4 + q;
            attc[((size_t)(n * LL + r)) * DD + hh * DK + d] = f2b(av[jn][q] * invq[q]);
        }
    }
}

// ---------------------------------------------------------------------------
// out = LayerNorm(a + b) * g + be ; writes f32 out and bf16 mirror
// ---------------------------------------------------------------------------
__global__ __launch_bounds__(256)
void add_ln(const float* __restrict__ a, const float* __restrict__ b,
            const float* __restrict__ g, const float* __restrict__ be,
            float* __restrict__ out, unsigned short* __restrict__ outb) {
    int m = blockIdx.x;
    int j = threadIdx.x;
    float x = a[(size_t)m * DD + j] + b[(size_t)m * DD + j];
    __shared__ float red[4];
    int wid = j >> 6;
    float s = x;
#pragma unroll
    for (int o = 32; o; o >>= 1) s += __shfl_xor(s, o);
    if ((j & 63) == 0) red[wid] = s;
    __syncthreads();
    float mean = (red[0] + red[1] + red[2] + red[3]) * (1.0f / 256.0f);
    float d = x - mean;
    float s2 = d * d;
#pragma unroll
    for (int o = 32; o; o >>= 1) s2 += __shfl_xor(s2, o);
    __syncthreads();
    if ((j & 63) == 0) red[wid] = s2;
    __syncthreads();
    float var = (red[0] + red[1] + red[2] + red[3]) * (1.0f / 256.0f);
    float r = d / sqrtf(var + 1e-5f) * g[j] + be[j];
    out[(size_t)m * DD + j] = r;
    outb[(size_t)m * DD + j] = f2b(r);
}

// ---------------------------------------------------------------------------
extern "C" void kernel_launch(void* const* d_in, const int* in_sizes, int n_in,
                              void* d_out, int out_size, void* d_ws, size_t ws_size,
                              hipStream_t stream) {
    const float* vehicles = (const float*)d_in[0];
    const float* fleet    = (const float*)d_in[1];
    const float* Wproj    = (const float*)d_in[2];
    const float* bproj    = (const float*)d_in[3];
    const float* Wq       = (const float*)d_in[4];
    const float* Wk       = (const float*)d_in[5];
    const float* Wv       = (const float*)d_in[6];
    const float* m1w      = (const float*)d_in[7];
    const float* m1b      = (const float*)d_in[8];
    const float* m2w      = (const float*)d_in[9];
    const float* m2b      = (const float*)d_in[10];
    const float* Wo       = (const float*)d_in[11];
    const float* bo       = (const float*)d_in[12];
    const float* n1_g     = (const float*)d_in[13];
    const float* n1_b     = (const float*)d_in[14];
    const float* ff1_w    = (const float*)d_in[15];
    const float* ff1_b    = (const float*)d_in[16];
    const float* ff2_w    = (const float*)d_in[17];
    const float* ff2_b    = (const float*)d_in[18];
    const float* n2_g     = (const float*)d_in[19];
    const float* n2_b     = (const float*)d_in[20];

    const size_t MROWS = (size_t)NB * LL;           // 8192
    const size_t HSZ   = MROWS * DD;                // 2,097,152

    float* ws = (float*)d_ws;
    float* h    = ws;                                // HSZ f32
    float* tmp  = h + HSZ;                           // HSZ f32
    float* cost = tmp + HSZ;                         // 1,048,576 f32
    unsigned short* hb    = (unsigned short*)(cost + 1048576);      // HSZ bf16
    unsigned short* attc  = hb + HSZ;                               // HSZ bf16
    unsigned short* qbb   = attc + HSZ;                             // HSZ bf16
    unsigned short* kbb   = qbb + HSZ;                              // HSZ bf16
    unsigned short* vtb   = kbb + HSZ;                              // HSZ bf16
    unsigned short* ffmid = vtb + HSZ;                              // M*FF bf16
    unsigned short* Wt    = ffmid + MROWS * FF;                     // 3*786432 bf16
    unsigned long long* mb64 = (unsigned long long*)(Wt + 3 * 786432); // 8192*2 u64

    const long WLS = 786432;   // per-layer transposed-weight stride (elems)

    // preprocessing
    pack_cost<<<1024, 256, 0, stream>>>(fleet, cost);
    proj_kernel<<<MROWS, 256, 0, stream>>>(vehicles, Wproj, bproj, h, hb);
    knn2<<<2048, 256, 0, stream>>>(cost, mb64);

    transposeW<<<dim3(8, 8, 3),  256, 0, stream>>>(Wq,    Wt + 0,      DD, DD, DD * DD, WLS);
    transposeW<<<dim3(8, 8, 3),  256, 0, stream>>>(Wk,    Wt + 65536,  DD, DD, DD * DD, WLS);
    transposeW<<<dim3(8, 8, 3),  256, 0, stream>>>(Wv,    Wt + 131072, DD, DD, DD * DD, WLS);
    transposeW<<<dim3(8, 8, 3),  256, 0, stream>>>(Wo,    Wt + 196608, DD, DD, DD * DD, WLS);
    transposeW<<<dim3(32, 8, 3), 256, 0, stream>>>(ff1_w, Wt + 262144, DD, FF, DD * FF, WLS);
    transposeW<<<dim3(8, 32, 3), 256, 0, stream>>>(ff2_w, Wt + 524288, FF, DD, FF * DD, WLS);

    dim3 gqkv(12, 64);   // qkv3: N=768, 128x64 tiles
    dim3 g256(4, 64);    // mmfma128: N=256
    dim3 gff1(8, 64);    // mmfma256relu: N=1024, 128x128 tiles

    for (int i = 0; i < LC; ++i) {
        const unsigned short* wt = Wt + (size_t)i * WLS;

        qkv3<<<gqkv, 256, 0, stream>>>(hb, wt, qbb, kbb, vtb);

        fattn5<<<NB * HH * 4, 128, 0, stream>>>(
            qbb, kbb, vtb, cost, mb64,
            m1w + (size_t)i * HH * 2 * MS, m1b + (size_t)i * HH * MS,
            m2w + (size_t)i * HH * MS,     m2b + (size_t)i * HH,
            attc);

        mmfma128<0><<<g256, 256, 0, stream>>>(attc, wt + 196608, bo + (size_t)i * DD,
                                              tmp, (int)MROWS, DD, DD);
        add_ln<<<MROWS, 256, 0, stream>>>(h, tmp, n1_g + (size_t)i * DD,
                                          n1_b + (size_t)i * DD, h, hb);

        mmfma256relu<<<gff1, 256, 0, stream>>>(hb, wt + 262144, ff1_b + (size_t)i * FF,
                                               ffmid, (int)MROWS, FF, DD);
        mmfma128<0><<<g256, 256, 0, stream>>>(ffmid, wt + 524288, ff2_b + (size_t)i * DD,
                                              tmp, (int)MROWS, DD, FF);

        float* dst = (i == LC - 1) ? (float*)d_out : h;
        add_ln<<<MROWS, 256, 0, stream>>>(h, tmp, n2_g + (size_t)i * DD,
                                          n2_b + (size_t)i * DD, dst, hb);
    }
}

// Round 7
// 349.039 us; speedup vs baseline: 1.0196x; 1.0196x over previous
//
#include <hip/hip_runtime.h>
#include <math.h>

// Problem constants
#define NB 64    // N batch
#define LL 128   // L
#define DV 16
#define DD 256   // D
#define HH 8     // heads
#define DK 32    // D/H
#define FF 1024
#define LC 3
#define KNN 6
#define MS 16
#define WLS 786432   // per-layer transposed-weight stride (elems)

typedef __attribute__((ext_vector_type(8))) short s16x8;   // 8 bf16 (4 VGPR)
typedef __attribute__((ext_vector_type(4))) float f32x4;   // MFMA acc

static __device__ inline unsigned short f2b(float x) {
    union { float f; unsigned int u; } v; v.f = x;
    unsigned int r = (v.u + 0x7FFFu + ((v.u >> 16) & 1u)) >> 16;
    return (unsigned short)r;
}
static __device__ inline float b2f(unsigned short u) {
    union { unsigned int u; float f; } v; v.u = ((unsigned int)u) << 16;
    return v.f;
}

// ---------------------------------------------------------------------------
// Input projection: 4 rows/block, wave-per-row. h f32 + hb bf16.
// ---------------------------------------------------------------------------
__global__ __launch_bounds__(256)
void proj2(const float* __restrict__ veh, const float* __restrict__ Wp,
           const float* __restrict__ bp, float* __restrict__ h,
           unsigned short* __restrict__ hb) {
    int m = blockIdx.x * 4 + (threadIdx.x >> 6);
    int l = threadIdx.x & 63;
    int c0 = l * 4;
    const float4* w4 = reinterpret_cast<const float4*>(Wp);   // [t*64 + l]
    float4 a = *reinterpret_cast<const float4*>(bp + c0);
    const float* vr = veh + (size_t)m * DV;
#pragma unroll
    for (int t = 0; t < DV; ++t) {
        float vt = vr[t];
        float4 wv = w4[t * 64 + l];
        a.x += vt * wv.x; a.y += vt * wv.y; a.z += vt * wv.z; a.w += vt * wv.w;
    }
    *reinterpret_cast<float4*>(h + (size_t)m * DD + c0) = a;
    ushort4 u; u.x = f2b(a.x); u.y = f2b(a.y); u.z = f2b(a.z); u.w = f2b(a.w);
    *reinterpret_cast<ushort4*>(hb + (size_t)m * DD + c0) = u;
}

// ---------------------------------------------------------------------------
// Pack cost = edges[...,0] into contiguous f32 (for knn) + bf16 (for attn)
// ---------------------------------------------------------------------------
__global__ __launch_bounds__(256)
void pack_cost2(const float* __restrict__ edges, float* __restrict__ cost,
                unsigned short* __restrict__ costb) {
    int t = blockIdx.x * 256 + threadIdx.x;
    const float4* e4 = reinterpret_cast<const float4*>(edges) + (size_t)t * 4;
    float4 a = e4[0], b = e4[1], c = e4[2], d = e4[3];
    float4 v = make_float4(a.x, b.x, c.x, d.x);
    reinterpret_cast<float4*>(cost)[t] = v;
    ushort4 u; u.x = f2b(v.x); u.y = f2b(v.y); u.z = f2b(v.z); u.w = f2b(v.w);
    reinterpret_cast<ushort4*>(costb)[t] = u;
}

// ---------------------------------------------------------------------------
// kNN mask as u64 bitmap (bit=1 -> blocked). f32 cost for exact tie-break.
// ---------------------------------------------------------------------------
__global__ __launch_bounds__(256)
void knn2(const float* __restrict__ cost, unsigned long long* __restrict__ mb64) {
    int row = blockIdx.x * 4 + (threadIdx.x >> 6);
    int lane = threadIdx.x & 63;
    const float* cr = cost + (size_t)row * LL;
    float v0 = cr[lane], v1 = cr[lane + 64];
    int i0 = lane, i1 = lane + 64;
    bool s0 = false, s1 = false;
#pragma unroll
    for (int k = 0; k < KNN; ++k) {
        float v; int i;
        if (v1 < v0) { v = v1; i = i1; } else { v = v0; i = i0; }
#pragma unroll
        for (int o = 1; o < 64; o <<= 1) {
            float ov = __shfl_xor(v, o);
            int oi = __shfl_xor(i, o);
            if (ov < v || (ov == v && oi < i)) { v = ov; i = oi; }
        }
        if (i == i0) { s0 = true; v0 = 3.4e38f; }
        if (i == i1) { s1 = true; v1 = 3.4e38f; }
    }
    unsigned long long b0 = __ballot(s0);
    unsigned long long b1 = __ballot(s1);
    if (lane == 0) {
        mb64[(size_t)row * 2 + 0] = ~b0;
        mb64[(size_t)row * 2 + 1] = ~b1;
    }
}

// ---------------------------------------------------------------------------
// Transpose + bf16-cast the four 256x256 weights x 3 layers in one dispatch.
// z = l*4 + w ; w selects {Wq,Wk,Wv,Wo}; out offset w*65536 within layer.
// ---------------------------------------------------------------------------
__global__ __launch_bounds__(256)
void transposeW4(const float* __restrict__ W0, const float* __restrict__ W1,
                 const float* __restrict__ W2, const float* __restrict__ W3,
                 unsigned short* __restrict__ out) {
    int z = blockIdx.z;
    int ll = z >> 2, w = z & 3;
    const float* src = (w == 0) ? W0 : (w == 1) ? W1 : (w == 2) ? W2 : W3;
    src += (size_t)ll * DD * DD;
    unsigned short* dst = out + (size_t)ll * WLS + (size_t)w * 65536;
    int tx = threadIdx.x & 31, ty = threadIdx.x >> 5;
    int k0 = blockIdx.y * 32, n0 = blockIdx.x * 32;
    __shared__ float T[32][33];
#pragma unroll
    for (int r = 0; r < 4; ++r)
        T[ty + r * 8][tx] = src[(size_t)(k0 + ty + r * 8) * DD + n0 + tx];
    __syncthreads();
#pragma unroll
    for (int r = 0; r < 4; ++r)
        dst[(size_t)(n0 + ty + r * 8) * DD + k0 + tx] = f2b(T[tx][ty + r * 8]);
}

// generic transpose for ff1/ff2
__global__ __launch_bounds__(256)
void transposeW(const float* __restrict__ in, unsigned short* __restrict__ out,
                int K, int N, long in_lstride, long out_lstride) {
    int l = blockIdx.z;
    const float* inp = in + (size_t)l * in_lstride;
    unsigned short* outp = out + (size_t)l * out_lstride;
    int tx = threadIdx.x & 31, ty = threadIdx.x >> 5;
    int k0 = blockIdx.y * 32, n0 = blockIdx.x * 32;
    __shared__ float T[32][33];
#pragma unroll
    for (int r = 0; r < 4; ++r)
        T[ty + r * 8][tx] = inp[(size_t)(k0 + ty + r * 8) * N + n0 + tx];
    __syncthreads();
#pragma unroll
    for (int r = 0; r < 4; ++r)
        outp[(size_t)(n0 + ty + r * 8) * K + k0 + tx] = f2b(T[tx][ty + r * 8]);
}

// ---------------------------------------------------------------------------
// MFMA GEMM, 128x64 tile. MODE 0: f32 out. MODE 1: bf16+relu.
// ---------------------------------------------------------------------------
template <int MODE>
__global__ __launch_bounds__(256)
void mmfma128(const unsigned short* __restrict__ A, const unsigned short* __restrict__ Bt,
              const float* __restrict__ bias, void* __restrict__ Cout,
              int M, int N, int K) {
    __shared__ unsigned short As[128 * 40];
    __shared__ unsigned short Bs[64 * 40];
    int tid = threadIdx.x;
    int w = tid >> 6, l = tid & 63;
    int lr = l & 15, lg = l >> 4;
    int m0 = blockIdx.y * 128, n0 = blockIdx.x * 64;
    int row = tid >> 2, seg = tid & 3;

    f32x4 acc[2][4];
#pragma unroll
    for (int i = 0; i < 2; ++i)
#pragma unroll
        for (int j = 0; j < 4; ++j) acc[i][j] = (f32x4)(0.f);

    for (int k0 = 0; k0 < K; k0 += 32) {
        int4 a0 = *reinterpret_cast<const int4*>(A  + (size_t)(m0 + row) * K + k0 + seg * 8);
        int4 a1 = *reinterpret_cast<const int4*>(A  + (size_t)(m0 + 64 + row) * K + k0 + seg * 8);
        int4 bv = *reinterpret_cast<const int4*>(Bt + (size_t)(n0 + row) * K + k0 + seg * 8);
        __syncthreads();
        *reinterpret_cast<int4*>(As + row * 40 + seg * 8) = a0;
        *reinterpret_cast<int4*>(As + (64 + row) * 40 + seg * 8) = a1;
        *reinterpret_cast<int4*>(Bs + row * 40 + seg * 8) = bv;
        __syncthreads();
        s16x8 af[2], bf[4];
#pragma unroll
        for (int i = 0; i < 2; ++i)
            af[i] = *reinterpret_cast<const s16x8*>(As + (w * 32 + i * 16 + lr) * 40 + lg * 8);
#pragma unroll
        for (int j = 0; j < 4; ++j)
            bf[j] = *reinterpret_cast<const s16x8*>(Bs + (j * 16 + lr) * 40 + lg * 8);
#pragma unroll
        for (int i = 0; i < 2; ++i)
#pragma unroll
            for (int j = 0; j < 4; ++j)
                acc[i][j] = __builtin_amdgcn_mfma_f32_16x16x32_bf16(af[i], bf[j], acc[i][j], 0, 0, 0);
    }

#pragma unroll
    for (int i = 0; i < 2; ++i)
#pragma unroll
        for (int j = 0; j < 4; ++j) {
            int col = n0 + j * 16 + lr;
            float bv = bias[col];
#pragma unroll
            for (int q = 0; q < 4; ++q) {
                int r = m0 + w * 32 + i * 16 + lg * 4 + q;
                float v = acc[i][j][q] + bv;
                if (MODE == 1) {
                    v = fmaxf(v, 0.f);
                    ((unsigned short*)Cout)[(size_t)r * N + col] = f2b(v);
                } else {
                    ((float*)Cout)[(size_t)r * N + col] = v;
                }
            }
        }
}

// ---------------------------------------------------------------------------
// MFMA GEMM, 128x128 tile (FF1): bf16 out + bias + relu.
// ---------------------------------------------------------------------------
__global__ __launch_bounds__(256)
void mmfma256relu(const unsigned short* __restrict__ A, const unsigned short* __restrict__ Bt,
                  const float* __restrict__ bias, unsigned short* __restrict__ Cout,
                  int M, int N, int K) {
    __shared__ unsigned short As[128 * 40];
    __shared__ unsigned short Bs[128 * 40];
    int tid = threadIdx.x;
    int w = tid >> 6, l = tid & 63;
    int wr = w >> 1, wc = w & 1;
    int lr = l & 15, lg = l >> 4;
    int m0 = blockIdx.y * 128, n0 = blockIdx.x * 128;

    f32x4 acc[4][4];
#pragma unroll
    for (int i = 0; i < 4; ++i)
#pragma unroll
        for (int j = 0; j < 4; ++j) acc[i][j] = (f32x4)(0.f);

    for (int k0 = 0; k0 < K; k0 += 32) {
        int4 a[2], b[2];
#pragma unroll
        for (int it = 0; it < 2; ++it) {
            int task = tid + it * 256;
            int row = task >> 2, seg = task & 3;
            a[it] = *reinterpret_cast<const int4*>(A  + (size_t)(m0 + row) * K + k0 + seg * 8);
            b[it] = *reinterpret_cast<const int4*>(Bt + (size_t)(n0 + row) * K + k0 + seg * 8);
        }
        __syncthreads();
#pragma unroll
        for (int it = 0; it < 2; ++it) {
            int task = tid + it * 256;
            int row = task >> 2, seg = task & 3;
            *reinterpret_cast<int4*>(As + row * 40 + seg * 8) = a[it];
            *reinterpret_cast<int4*>(Bs + row * 40 + seg * 8) = b[it];
        }
        __syncthreads();
        s16x8 af[4], bf[4];
#pragma unroll
        for (int i = 0; i < 4; ++i)
            af[i] = *reinterpret_cast<const s16x8*>(As + (wr * 64 + i * 16 + lr) * 40 + lg * 8);
#pragma unroll
        for (int j = 0; j < 4; ++j)
            bf[j] = *reinterpret_cast<const s16x8*>(Bs + (wc * 64 + j * 16 + lr) * 40 + lg * 8);
#pragma unroll
        for (int i = 0; i < 4; ++i)
#pragma unroll
            for (int j = 0; j < 4; ++j)
                acc[i][j] = __builtin_amdgcn_mfma_f32_16x16x32_bf16(af[i], bf[j], acc[i][j], 0, 0, 0);
    }

#pragma unroll
    for (int i = 0; i < 4; ++i)
#pragma unroll
        for (int j = 0; j < 4; ++j) {
            int col = n0 + wc * 64 + j * 16 + lr;
            float bv = bias[col];
#pragma unroll
            for (int q = 0; q < 4; ++q) {
                int r = m0 + wr * 64 + i * 16 + lg * 4 + q;
                float v = fmaxf(acc[i][j][q] + bv, 0.f);
                Cout[(size_t)r * N + col] = f2b(v);
            }
        }
}

// ---------------------------------------------------------------------------
// Unified QKV GEMM (N=768). q,k head-major [bh][128][32]; v^T [bh][32][128].
// ---------------------------------------------------------------------------
__global__ __launch_bounds__(256)
void qkv3(const unsigned short* __restrict__ A, const unsigned short* __restrict__ Bt,
          unsigned short* __restrict__ qb, unsigned short* __restrict__ kb,
          unsigned short* __restrict__ vtb) {
    const int K = DD;
    __shared__ unsigned short As[128 * 40];
    __shared__ unsigned short Bs[64 * 40];
    int tid = threadIdx.x;
    int w = tid >> 6, l = tid & 63;
    int lr = l & 15, lg = l >> 4;
    int m0 = blockIdx.y * 128, n0 = blockIdx.x * 64;
    int row = tid >> 2, seg = tid & 3;

    f32x4 acc[2][4];
#pragma unroll
    for (int i = 0; i < 2; ++i)
#pragma unroll
        for (int j = 0; j < 4; ++j) acc[i][j] = (f32x4)(0.f);

    for (int k0 = 0; k0 < K; k0 += 32) {
        int4 a0 = *reinterpret_cast<const int4*>(A  + (size_t)(m0 + row) * K + k0 + seg * 8);
        int4 a1 = *reinterpret_cast<const int4*>(A  + (size_t)(m0 + 64 + row) * K + k0 + seg * 8);
        int4 bv = *reinterpret_cast<const int4*>(Bt + (size_t)(n0 + row) * K + k0 + seg * 8);
        __syncthreads();
        *reinterpret_cast<int4*>(As + row * 40 + seg * 8) = a0;
        *reinterpret_cast<int4*>(As + (64 + row) * 40 + seg * 8) = a1;
        *reinterpret_cast<int4*>(Bs + row * 40 + seg * 8) = bv;
        __syncthreads();
        s16x8 af[2], bf[4];
#pragma unroll
        for (int i = 0; i < 2; ++i)
            af[i] = *reinterpret_cast<const s16x8*>(As + (w * 32 + i * 16 + lr) * 40 + lg * 8);
#pragma unroll
        for (int j = 0; j < 4; ++j)
            bf[j] = *reinterpret_cast<const s16x8*>(Bs + (j * 16 + lr) * 40 + lg * 8);
#pragma unroll
        for (int i = 0; i < 2; ++i)
#pragma unroll
            for (int j = 0; j < 4; ++j)
                acc[i][j] = __builtin_amdgcn_mfma_f32_16x16x32_bf16(af[i], bf[j], acc[i][j], 0, 0, 0);
    }

    int s = n0 >> 8;          // 0=q, 1=k, 2=v (block-uniform)
    int nn = blockIdx.y;
#pragma unroll
    for (int i = 0; i < 2; ++i)
#pragma unroll
        for (int j = 0; j < 4; ++j) {
            int cc = (n0 & 255) + j * 16 + lr;
            int hh = cc >> 5, dk = cc & 31;
            int rl = w * 32 + i * 16 + lg * 4;
            if (s == 2) {
                ushort4 u;
                u.x = f2b(acc[i][j][0]); u.y = f2b(acc[i][j][1]);
                u.z = f2b(acc[i][j][2]); u.w = f2b(acc[i][j][3]);
                *reinterpret_cast<ushort4*>(
                    vtb + ((size_t)(nn * HH + hh) * DK + dk) * LL + rl) = u;
            } else {
                unsigned short* dst = s ? kb : qb;
                size_t ho = ((size_t)(nn * HH + hh) * LL + rl) * DK + dk;
#pragma unroll
                for (int q = 0; q < 4; ++q)
                    dst[ho + (size_t)q * DK] = f2b(acc[i][j][q]);
            }
        }
}

// ---------------------------------------------------------------------------
// Fused attention v6: column-split. Block = 2 waves over (bh, 16 rows);
// wave cw owns cols cw*64..+63. 8192 waves total. Cost staged bf16 in LDS,
// mask as 16-bit reg, cross-wave softmax merge + PV partial sum via LDS.
// ---------------------------------------------------------------------------
__global__ __launch_bounds__(128)
void fattn6(const unsigned short* __restrict__ qb, const unsigned short* __restrict__ kb,
            const unsigned short* __restrict__ vtb, const unsigned short* __restrict__ costb,
            const unsigned long long* __restrict__ mb64,
            const float* __restrict__ m1w, const float* __restrict__ m1b,
            const float* __restrict__ m2w, const float* __restrict__ m2b,
            unsigned short* __restrict__ attc) {
    int x = blockIdx.x;
    int bh = x >> 3, rg = x & 7;
    int n = bh >> 3, hh = bh & 7;
    int tid = threadIdx.x;
    int cw = tid >> 6, l = tid & 63;
    int lr = l & 15, lg = l >> 4;
    int rbase = rg * 16;

    __shared__ unsigned short Cs[16 * 136];     // cost bf16, stride 136
    __shared__ unsigned short Pls[2][16 * 72];  // P bf16 per wave, stride 72
    __shared__ float Pv[2][16 * 36];            // PV partials, stride 36
    __shared__ float MSx[16][2], MSs[16][2];    // per-row (max, sum)

    // stage cost slice (16x128 bf16), coalesced
    const unsigned short* cg = costb + ((size_t)(n * LL) + rbase) * LL;
#pragma unroll
    for (int it = 0; it < 2; ++it) {
        int task = tid + it * 128;
        int row = task >> 4, seg = task & 15;
        *reinterpret_cast<int4*>(&Cs[row * 136 + seg * 8]) =
            *reinterpret_cast<const int4*>(cg + row * 128 + seg * 8);
    }

    // QK^T over this wave's 64 cols
    s16x8 aq = *reinterpret_cast<const s16x8*>(
        qb + ((size_t)bh * LL + rbase + lr) * DK + lg * 8);
    const unsigned short* kgw = kb + ((size_t)bh * LL + cw * 64) * DK;
    f32x4 acc[4];
#pragma unroll
    for (int j = 0; j < 4; ++j) acc[j] = (f32x4)(0.f);
#pragma unroll
    for (int j = 0; j < 4; ++j) {
        s16x8 bk = *reinterpret_cast<const s16x8*>(kgw + (j * 16 + lr) * DK + lg * 8);
        acc[j] = __builtin_amdgcn_mfma_f32_16x16x32_bf16(aq, bk, acc[j], 0, 0, 0);
    }

    // mask bits for this lane's 16 elements
    unsigned mbits = 0;
#pragma unroll
    for (int q = 0; q < 4; ++q) {
        unsigned long long raw =
            mb64[((size_t)(n * LL) + rbase + lg * 4 + q) * 2 + cw] >> lr;
#pragma unroll
        for (int j = 0; j < 4; ++j)
            mbits |= (unsigned)((raw >> (j * 16)) & 1ull) << (q * 4 + j);
    }

    __syncthreads();   // cost staged

    // mixer MLP (scalar weights), elem-at-a-time; score overwrites acc
    const float scale = 0.17677669529663687f;  // 1/sqrt(32)
    const float* w0g = m1w + (hh * 2 + 0) * MS;
    const float* w1g = m1w + (hh * 2 + 1) * MS;
    const float* b1g = m1b + hh * MS;
    const float* w2g = m2w + hh * MS;
    float b2v = m2b[hh];
#pragma unroll
    for (int j = 0; j < 4; ++j)
#pragma unroll
        for (int q = 0; q < 4; ++q) {
            float dt = acc[j][q] * scale;
            float cst = b2f(Cs[(lg * 4 + q) * 136 + cw * 64 + j * 16 + lr]);
            float s = b2v;
#pragma unroll
            for (int m = 0; m < MS; ++m)
                s += fmaxf(dt * w0g[m] + cst * w1g[m] + b1g[m], 0.f) * w2g[m];
            if ((mbits >> (q * 4 + j)) & 1u) s = -1e9f;
            acc[j][q] = s;
        }

    // local softmax per row over (j x 16 lanes); e overwrites acc
    float mxl[4], sml[4];
#pragma unroll
    for (int q = 0; q < 4; ++q) {
        float mx = fmaxf(fmaxf(acc[0][q], acc[1][q]), fmaxf(acc[2][q], acc[3][q]));
#pragma unroll
        for (int o = 1; o < 16; o <<= 1) mx = fmaxf(mx, __shfl_xor(mx, o));
        float sum = 0.f;
#pragma unroll
        for (int j = 0; j < 4; ++j) {
            float e = __expf(acc[j][q] - mx);
            acc[j][q] = e; sum += e;
        }
#pragma unroll
        for (int o = 1; o < 16; o <<= 1) sum += __shfl_xor(sum, o);
        mxl[q] = mx; sml[q] = sum;
    }
    if (lr == 0) {
#pragma unroll
        for (int q = 0; q < 4; ++q) {
            MSx[lg * 4 + q][cw] = mxl[q];
            MSs[lg * 4 + q][cw] = sml[q];
        }
    }
    __syncthreads();   // exchange (max,sum)

    // merge halves; write scaled P
#pragma unroll
    for (int q = 0; q < 4; ++q) {
        int row = lg * 4 + q;
        float m0 = MSx[row][0], m1 = MSx[row][1];
        float s0 = MSs[row][0], s1 = MSs[row][1];
        float m12 = fmaxf(m0, m1);
        float tot = s0 * __expf(m0 - m12) + s1 * __expf(m1 - m12);
        float myscale = __expf(mxl[q] - m12) / tot;
#pragma unroll
        for (int j = 0; j < 4; ++j)
            Pls[cw][row * 72 + j * 16 + lr] = f2b(acc[j][q] * myscale);
    }

    // PV partial over this wave's 64 K-cols
    const unsigned short* vg = vtb + (size_t)bh * DK * LL;
    f32x4 av[2];
    av[0] = (f32x4)(0.f); av[1] = (f32x4)(0.f);
#pragma unroll
    for (int ks = 0; ks < 2; ++ks) {
        s16x8 ap = *reinterpret_cast<const s16x8*>(&Pls[cw][lr * 72 + ks * 32 + lg * 8]);
#pragma unroll
        for (int jn = 0; jn < 2; ++jn) {
            s16x8 bv = *reinterpret_cast<const s16x8*>(
                vg + (jn * 16 + lr) * LL + cw * 64 + ks * 32 + lg * 8);
            av[jn] = __builtin_amdgcn_mfma_f32_16x16x32_bf16(ap, bv, av[jn], 0, 0, 0);
        }
    }
#pragma unroll
    for (int jn = 0; jn < 2; ++jn)
#pragma unroll
        for (int q = 0; q < 4; ++q)
            Pv[cw][(lg * 4 + q) * 36 + jn * 16 + lr] = av[jn][q];
    __syncthreads();   // partials ready

    // combine + write output
    int rl = tid >> 3, d0 = (tid & 7) * 4;
    float4 p0 = *reinterpret_cast<const float4*>(&Pv[0][rl * 36 + d0]);
    float4 p1 = *reinterpret_cast<const float4*>(&Pv[1][rl * 36 + d0]);
    ushort4 u;
    u.x = f2b(p0.x + p1.x); u.y = f2b(p0.y + p1.y);
    u.z = f2b(p0.z + p1.z); u.w = f2b(p0.w + p1.w);
    *reinterpret_cast<ushort4*>(
        attc + ((size_t)(n * LL) + rbase + rl) * DD + hh * DK + d0) = u;
}

// ---------------------------------------------------------------------------
// out = LayerNorm(a + b) * g + be ; wave-per-row, no barriers.
// ---------------------------------------------------------------------------
__global__ __launch_bounds__(256)
void add_ln2(const float* __restrict__ a, const float* __restrict__ b,
             const float* __restrict__ g, const float* __restrict__ be,
             float* __restrict__ out, unsigned short* __restrict__ outb) {
    int m = blockIdx.x * 4 + (threadIdx.x >> 6);
    int l = threadIdx.x & 63;
    size_t off = (size_t)m * DD + l * 4;
    float4 av = *reinterpret_cast<const float4*>(a + off);
    float4 bv = *reinterpret_cast<const float4*>(b + off);
    float4 x = make_float4(av.x + bv.x, av.y + bv.y, av.z + bv.z, av.w + bv.w);
    float s = x.x + x.y + x.z + x.w;
#pragma unroll
    for (int o = 1; o < 64; o <<= 1) s += __shfl_xor(s, o);
    float mean = s * (1.0f / 256.0f);
    float4 d = make_float4(x.x - mean, x.y - mean, x.z - mean, x.w - mean);
    float s2 = d.x * d.x + d.y * d.y + d.z * d.z + d.w * d.w;
#pragma unroll
    for (int o = 1; o < 64; o <<= 1) s2 += __shfl_xor(s2, o);
    float inv = 1.f / sqrtf(s2 * (1.0f / 256.0f) + 1e-5f);
    float4 gv = *reinterpret_cast<const float4*>(g + l * 4);
    float4 ev = *reinterpret_cast<const float4*>(be + l * 4);
    float4 r = make_float4(d.x * inv * gv.x + ev.x, d.y * inv * gv.y + ev.y,
                           d.z * inv * gv.z + ev.z, d.w * inv * gv.w + ev.w);
    *reinterpret_cast<float4*>(out + off) = r;
    ushort4 u; u.x = f2b(r.x); u.y = f2b(r.y); u.z = f2b(r.z); u.w = f2b(r.w);
    *reinterpret_cast<ushort4*>(outb + off) = u;
}

// ---------------------------------------------------------------------------
extern "C" void kernel_launch(void* const* d_in, const int* in_sizes, int n_in,
                              void* d_out, int out_size, void* d_ws, size_t ws_size,
                              hipStream_t stream) {
    const float* vehicles = (const float*)d_in[0];
    const float* fleet    = (const float*)d_in[1];
    const float* Wproj    = (const float*)d_in[2];
    const float* bproj    = (const float*)d_in[3];
    const float* Wq       = (const float*)d_in[4];
    const float* Wk       = (const float*)d_in[5];
    const float* Wv       = (const float*)d_in[6];
    const float* m1w      = (const float*)d_in[7];
    const float* m1b      = (const float*)d_in[8];
    const float* m2w      = (const float*)d_in[9];
    const float* m2b      = (const float*)d_in[10];
    const float* Wo       = (const float*)d_in[11];
    const float* bo       = (const float*)d_in[12];
    const float* n1_g     = (const float*)d_in[13];
    const float* n1_b     = (const float*)d_in[14];
    const float* ff1_w    = (const float*)d_in[15];
    const float* ff1_b    = (const float*)d_in[16];
    const float* ff2_w    = (const float*)d_in[17];
    const float* ff2_b    = (const float*)d_in[18];
    const float* n2_g     = (const float*)d_in[19];
    const float* n2_b     = (const float*)d_in[20];

    const size_t MROWS = (size_t)NB * LL;           // 8192
    const size_t HSZ   = MROWS * DD;                // 2,097,152

    float* ws = (float*)d_ws;
    float* h    = ws;                                // HSZ f32
    float* tmp  = h + HSZ;                           // HSZ f32
    float* cost = tmp + HSZ;                         // 1,048,576 f32
    unsigned short* hb    = (unsigned short*)(cost + 1048576);      // HSZ bf16
    unsigned short* attc  = hb + HSZ;                               // HSZ bf16
    unsigned short* qbb   = attc + HSZ;                             // HSZ bf16
    unsigned short* kbb   = qbb + HSZ;                              // HSZ bf16
    unsigned short* vtb   = kbb + HSZ;                              // HSZ bf16
    unsigned short* ffmid = vtb + HSZ;                              // M*FF bf16
    unsigned short* Wt    = ffmid + MROWS * FF;                     // 3*WLS bf16
    unsigned long long* mb64 = (unsigned long long*)(Wt + 3 * WLS); // 16384 u64
    unsigned short* costb = (unsigned short*)(mb64 + 16384);        // 1,048,576 bf16

    // preprocessing
    pack_cost2<<<1024, 256, 0, stream>>>(fleet, cost, costb);
    proj2<<<2048, 256, 0, stream>>>(vehicles, Wproj, bproj, h, hb);
    knn2<<<2048, 256, 0, stream>>>(cost, mb64);

    transposeW4<<<dim3(8, 8, 12), 256, 0, stream>>>(Wq, Wk, Wv, Wo, Wt);
    transposeW<<<dim3(32, 8, 3), 256, 0, stream>>>(ff1_w, Wt + 262144, DD, FF, DD * FF, WLS);
    transposeW<<<dim3(8, 32, 3), 256, 0, stream>>>(ff2_w, Wt + 524288, FF, DD, FF * DD, WLS);

    dim3 gqkv(12, 64);   // qkv3: N=768, 128x64 tiles
    dim3 g256(4, 64);    // mmfma128: N=256
    dim3 gff1(8, 64);    // mmfma256relu: N=1024, 128x128 tiles

    for (int i = 0; i < LC; ++i) {
        const unsigned short* wt = Wt + (size_t)i * WLS;

        qkv3<<<gqkv, 256, 0, stream>>>(hb, wt, qbb, kbb, vtb);

        fattn6<<<NB * HH * 8, 128, 0, stream>>>(
            qbb, kbb, vtb, costb, mb64,
            m1w + (size_t)i * HH * 2 * MS, m1b + (size_t)i * HH * MS,
            m2w + (size_t)i * HH * MS,     m2b + (size_t)i * HH,
            attc);

        mmfma128<0><<<g256, 256, 0, stream>>>(attc, wt + 196608, bo + (size_t)i * DD,
                                              tmp, (int)MROWS, DD, DD);
        add_ln2<<<2048, 256, 0, stream>>>(h, tmp, n1_g + (size_t)i * DD,
                                          n1_b + (size_t)i * DD, h, hb);

        mmfma256relu<<<gff1, 256, 0, stream>>>(hb, wt + 262144, ff1_b + (size_t)i * FF,
                                               ffmid, (int)MROWS, FF, DD);
        mmfma128<0><<<g256, 256, 0, stream>>>(ffmid, wt + 524288, ff2_b + (size_t)i * DD,
                                              tmp, (int)MROWS, DD, FF);

        float* dst = (i == LC - 1) ? (float*)d_out : h;
        add_ln2<<<2048, 256, 0, stream>>>(h, tmp, n2_g + (size_t)i * DD,
                                          n2_b + (size_t)i * DD, dst, hb);
    }
}

// Round 8
// 320.261 us; speedup vs baseline: 1.1112x; 1.0899x over previous
//
#include <hip/hip_runtime.h>
#include <math.h>

// Problem constants
#define NB 64    // N batch
#define LL 128   // L
#define DV 16
#define DD 256   // D
#define HH 8     // heads
#define DK 32    // D/H
#define FF 1024
#define LC 3
#define KNN 6
#define MS 16
#define WLS 786432   // per-layer transposed-weight stride (elems)

typedef __attribute__((ext_vector_type(8))) short s16x8;   // 8 bf16 (4 VGPR)
typedef __attribute__((ext_vector_type(4))) float f32x4;   // MFMA acc

static __device__ inline unsigned short f2b(float x) {
    union { float f; unsigned int u; } v; v.f = x;
    unsigned int r = (v.u + 0x7FFFu + ((v.u >> 16) & 1u)) >> 16;
    return (unsigned short)r;
}

// ---------------------------------------------------------------------------
// Input projection: 4 rows/block, wave-per-row. h f32 + hb bf16.
// ---------------------------------------------------------------------------
__global__ __launch_bounds__(256)
void proj2(const float* __restrict__ veh, const float* __restrict__ Wp,
           const float* __restrict__ bp, float* __restrict__ h,
           unsigned short* __restrict__ hb) {
    int m = blockIdx.x * 4 + (threadIdx.x >> 6);
    int l = threadIdx.x & 63;
    int c0 = l * 4;
    const float4* w4 = reinterpret_cast<const float4*>(Wp);   // [t*64 + l]
    float4 a = *reinterpret_cast<const float4*>(bp + c0);
    const float* vr = veh + (size_t)m * DV;
#pragma unroll
    for (int t = 0; t < DV; ++t) {
        float vt = vr[t];
        float4 wv = w4[t * 64 + l];
        a.x += vt * wv.x; a.y += vt * wv.y; a.z += vt * wv.z; a.w += vt * wv.w;
    }
    *reinterpret_cast<float4*>(h + (size_t)m * DD + c0) = a;
    ushort4 u; u.x = f2b(a.x); u.y = f2b(a.y); u.z = f2b(a.z); u.w = f2b(a.w);
    *reinterpret_cast<ushort4*>(hb + (size_t)m * DD + c0) = u;
}

// ---------------------------------------------------------------------------
// Pack cost = edges[...,0] into contiguous f32 (N,L,L)
// ---------------------------------------------------------------------------
__global__ __launch_bounds__(256)
void pack_cost(const float* __restrict__ edges, float* __restrict__ cost) {
    int t = blockIdx.x * 256 + threadIdx.x;
    const float4* e4 = reinterpret_cast<const float4*>(edges) + (size_t)t * 4;
    float4 a = e4[0], b = e4[1], c = e4[2], d = e4[3];
    reinterpret_cast<float4*>(cost)[t] = make_float4(a.x, b.x, c.x, d.x);
}

// ---------------------------------------------------------------------------
// kNN: pack the 6 selected indices (ascending dist, ties->lowest index,
// matching jax.lax.top_k on -dist) into one u64 per row (8 bits each).
// ---------------------------------------------------------------------------
__global__ __launch_bounds__(256)
void knn_idx(const float* __restrict__ cost, unsigned long long* __restrict__ idx8) {
    int row = blockIdx.x * 4 + (threadIdx.x >> 6);
    int lane = threadIdx.x & 63;
    const float* cr = cost + (size_t)row * LL;
    float v0 = cr[lane], v1 = cr[lane + 64];
    int i0 = lane, i1 = lane + 64;
    unsigned long long packed = 0;
#pragma unroll
    for (int k = 0; k < KNN; ++k) {
        float v; int i;
        if (v1 < v0) { v = v1; i = i1; } else { v = v0; i = i0; }
#pragma unroll
        for (int o = 1; o < 64; o <<= 1) {
            float ov = __shfl_xor(v, o);
            int oi = __shfl_xor(i, o);
            if (ov < v || (ov == v && oi < i)) { v = ov; i = oi; }
        }
        packed |= (unsigned long long)i << (k * 8);
        if (i == i0) v0 = 3.4e38f;
        if (i == i1) v1 = 3.4e38f;
    }
    if (lane == 0) idx8[row] = packed;
}

// ---------------------------------------------------------------------------
// Transpose + bf16-cast the four 256x256 weights x 3 layers in one dispatch.
// ---------------------------------------------------------------------------
__global__ __launch_bounds__(256)
void transposeW4(const float* __restrict__ W0, const float* __restrict__ W1,
                 const float* __restrict__ W2, const float* __restrict__ W3,
                 unsigned short* __restrict__ out) {
    int z = blockIdx.z;
    int ll = z >> 2, w = z & 3;
    const float* src = (w == 0) ? W0 : (w == 1) ? W1 : (w == 2) ? W2 : W3;
    src += (size_t)ll * DD * DD;
    unsigned short* dst = out + (size_t)ll * WLS + (size_t)w * 65536;
    int tx = threadIdx.x & 31, ty = threadIdx.x >> 5;
    int k0 = blockIdx.y * 32, n0 = blockIdx.x * 32;
    __shared__ float T[32][33];
#pragma unroll
    for (int r = 0; r < 4; ++r)
        T[ty + r * 8][tx] = src[(size_t)(k0 + ty + r * 8) * DD + n0 + tx];
    __syncthreads();
#pragma unroll
    for (int r = 0; r < 4; ++r)
        dst[(size_t)(n0 + ty + r * 8) * DD + k0 + tx] = f2b(T[tx][ty + r * 8]);
}

// generic transpose for ff1/ff2
__global__ __launch_bounds__(256)
void transposeW(const float* __restrict__ in, unsigned short* __restrict__ out,
                int K, int N, long in_lstride, long out_lstride) {
    int l = blockIdx.z;
    const float* inp = in + (size_t)l * in_lstride;
    unsigned short* outp = out + (size_t)l * out_lstride;
    int tx = threadIdx.x & 31, ty = threadIdx.x >> 5;
    int k0 = blockIdx.y * 32, n0 = blockIdx.x * 32;
    __shared__ float T[32][33];
#pragma unroll
    for (int r = 0; r < 4; ++r)
        T[ty + r * 8][tx] = inp[(size_t)(k0 + ty + r * 8) * N + n0 + tx];
    __syncthreads();
#pragma unroll
    for (int r = 0; r < 4; ++r)
        outp[(size_t)(n0 + ty + r * 8) * K + k0 + tx] = f2b(T[tx][ty + r * 8]);
}

// ---------------------------------------------------------------------------
// MFMA GEMM, 128x64 tile. MODE 0: f32 out. MODE 1: bf16+relu.
// ---------------------------------------------------------------------------
template <int MODE>
__global__ __launch_bounds__(256)
void mmfma128(const unsigned short* __restrict__ A, const unsigned short* __restrict__ Bt,
              const float* __restrict__ bias, void* __restrict__ Cout,
              int M, int N, int K) {
    __shared__ unsigned short As[128 * 40];
    __shared__ unsigned short Bs[64 * 40];
    int tid = threadIdx.x;
    int w = tid >> 6, l = tid & 63;
    int lr = l & 15, lg = l >> 4;
    int m0 = blockIdx.y * 128, n0 = blockIdx.x * 64;
    int row = tid >> 2, seg = tid & 3;

    f32x4 acc[2][4];
#pragma unroll
    for (int i = 0; i < 2; ++i)
#pragma unroll
        for (int j = 0; j < 4; ++j) acc[i][j] = (f32x4)(0.f);

    for (int k0 = 0; k0 < K; k0 += 32) {
        int4 a0 = *reinterpret_cast<const int4*>(A  + (size_t)(m0 + row) * K + k0 + seg * 8);
        int4 a1 = *reinterpret_cast<const int4*>(A  + (size_t)(m0 + 64 + row) * K + k0 + seg * 8);
        int4 bv = *reinterpret_cast<const int4*>(Bt + (size_t)(n0 + row) * K + k0 + seg * 8);
        __syncthreads();
        *reinterpret_cast<int4*>(As + row * 40 + seg * 8) = a0;
        *reinterpret_cast<int4*>(As + (64 + row) * 40 + seg * 8) = a1;
        *reinterpret_cast<int4*>(Bs + row * 40 + seg * 8) = bv;
        __syncthreads();
        s16x8 af[2], bf[4];
#pragma unroll
        for (int i = 0; i < 2; ++i)
            af[i] = *reinterpret_cast<const s16x8*>(As + (w * 32 + i * 16 + lr) * 40 + lg * 8);
#pragma unroll
        for (int j = 0; j < 4; ++j)
            bf[j] = *reinterpret_cast<const s16x8*>(Bs + (j * 16 + lr) * 40 + lg * 8);
#pragma unroll
        for (int i = 0; i < 2; ++i)
#pragma unroll
            for (int j = 0; j < 4; ++j)
                acc[i][j] = __builtin_amdgcn_mfma_f32_16x16x32_bf16(af[i], bf[j], acc[i][j], 0, 0, 0);
    }

#pragma unroll
    for (int i = 0; i < 2; ++i)
#pragma unroll
        for (int j = 0; j < 4; ++j) {
            int col = n0 + j * 16 + lr;
            float bv = bias[col];
#pragma unroll
            for (int q = 0; q < 4; ++q) {
                int r = m0 + w * 32 + i * 16 + lg * 4 + q;
                float v = acc[i][j][q] + bv;
                if (MODE == 1) {
                    v = fmaxf(v, 0.f);
                    ((unsigned short*)Cout)[(size_t)r * N + col] = f2b(v);
                } else {
                    ((float*)Cout)[(size_t)r * N + col] = v;
                }
            }
        }
}

// ---------------------------------------------------------------------------
// MFMA GEMM, 128x128 tile (FF1): bf16 out + bias + relu.
// ---------------------------------------------------------------------------
__global__ __launch_bounds__(256)
void mmfma256relu(const unsigned short* __restrict__ A, const unsigned short* __restrict__ Bt,
                  const float* __restrict__ bias, unsigned short* __restrict__ Cout,
                  int M, int N, int K) {
    __shared__ unsigned short As[128 * 40];
    __shared__ unsigned short Bs[128 * 40];
    int tid = threadIdx.x;
    int w = tid >> 6, l = tid & 63;
    int wr = w >> 1, wc = w & 1;
    int lr = l & 15, lg = l >> 4;
    int m0 = blockIdx.y * 128, n0 = blockIdx.x * 128;

    f32x4 acc[4][4];
#pragma unroll
    for (int i = 0; i < 4; ++i)
#pragma unroll
        for (int j = 0; j < 4; ++j) acc[i][j] = (f32x4)(0.f);

    for (int k0 = 0; k0 < K; k0 += 32) {
        int4 a[2], b[2];
#pragma unroll
        for (int it = 0; it < 2; ++it) {
            int task = tid + it * 256;
            int row = task >> 2, seg = task & 3;
            a[it] = *reinterpret_cast<const int4*>(A  + (size_t)(m0 + row) * K + k0 + seg * 8);
            b[it] = *reinterpret_cast<const int4*>(Bt + (size_t)(n0 + row) * K + k0 + seg * 8);
        }
        __syncthreads();
#pragma unroll
        for (int it = 0; it < 2; ++it) {
            int task = tid + it * 256;
            int row = task >> 2, seg = task & 3;
            *reinterpret_cast<int4*>(As + row * 40 + seg * 8) = a[it];
            *reinterpret_cast<int4*>(Bs + row * 40 + seg * 8) = b[it];
        }
        __syncthreads();
        s16x8 af[4], bf[4];
#pragma unroll
        for (int i = 0; i < 4; ++i)
            af[i] = *reinterpret_cast<const s16x8*>(As + (wr * 64 + i * 16 + lr) * 40 + lg * 8);
#pragma unroll
        for (int j = 0; j < 4; ++j)
            bf[j] = *reinterpret_cast<const s16x8*>(Bs + (wc * 64 + j * 16 + lr) * 40 + lg * 8);
#pragma unroll
        for (int i = 0; i < 4; ++i)
#pragma unroll
            for (int j = 0; j < 4; ++j)
                acc[i][j] = __builtin_amdgcn_mfma_f32_16x16x32_bf16(af[i], bf[j], acc[i][j], 0, 0, 0);
    }

#pragma unroll
    for (int i = 0; i < 4; ++i)
#pragma unroll
        for (int j = 0; j < 4; ++j) {
            int col = n0 + wc * 64 + j * 16 + lr;
            float bv = bias[col];
#pragma unroll
            for (int q = 0; q < 4; ++q) {
                int r = m0 + wr * 64 + i * 16 + lg * 4 + q;
                float v = fmaxf(acc[i][j][q] + bv, 0.f);
                Cout[(size_t)r * N + col] = f2b(v);
            }
        }
}

// ---------------------------------------------------------------------------
// Unified QKV GEMM (N=768). Outputs f32 head-major [bh][128][32] for q,k,v.
// ---------------------------------------------------------------------------
__global__ __launch_bounds__(256)
void qkv3(const unsigned short* __restrict__ A, const unsigned short* __restrict__ Bt,
          float* __restrict__ Oq, float* __restrict__ Ok, float* __restrict__ Ov) {
    const int K = DD;
    __shared__ unsigned short As[128 * 40];
    __shared__ unsigned short Bs[64 * 40];
    int tid = threadIdx.x;
    int w = tid >> 6, l = tid & 63;
    int lr = l & 15, lg = l >> 4;
    int m0 = blockIdx.y * 128, n0 = blockIdx.x * 64;
    int row = tid >> 2, seg = tid & 3;

    f32x4 acc[2][4];
#pragma unroll
    for (int i = 0; i < 2; ++i)
#pragma unroll
        for (int j = 0; j < 4; ++j) acc[i][j] = (f32x4)(0.f);

    for (int k0 = 0; k0 < K; k0 += 32) {
        int4 a0 = *reinterpret_cast<const int4*>(A  + (size_t)(m0 + row) * K + k0 + seg * 8);
        int4 a1 = *reinterpret_cast<const int4*>(A  + (size_t)(m0 + 64 + row) * K + k0 + seg * 8);
        int4 bv = *reinterpret_cast<const int4*>(Bt + (size_t)(n0 + row) * K + k0 + seg * 8);
        __syncthreads();
        *reinterpret_cast<int4*>(As + row * 40 + seg * 8) = a0;
        *reinterpret_cast<int4*>(As + (64 + row) * 40 + seg * 8) = a1;
        *reinterpret_cast<int4*>(Bs + row * 40 + seg * 8) = bv;
        __syncthreads();
        s16x8 af[2], bf[4];
#pragma unroll
        for (int i = 0; i < 2; ++i)
            af[i] = *reinterpret_cast<const s16x8*>(As + (w * 32 + i * 16 + lr) * 40 + lg * 8);
#pragma unroll
        for (int j = 0; j < 4; ++j)
            bf[j] = *reinterpret_cast<const s16x8*>(Bs + (j * 16 + lr) * 40 + lg * 8);
#pragma unroll
        for (int i = 0; i < 2; ++i)
#pragma unroll
            for (int j = 0; j < 4; ++j)
                acc[i][j] = __builtin_amdgcn_mfma_f32_16x16x32_bf16(af[i], bf[j], acc[i][j], 0, 0, 0);
    }

    int s = n0 >> 8;          // 0=q, 1=k, 2=v (block-uniform)
    int nn = blockIdx.y;
    float* dst = (s == 0) ? Oq : (s == 1) ? Ok : Ov;
#pragma unroll
    for (int i = 0; i < 2; ++i)
#pragma unroll
        for (int j = 0; j < 4; ++j) {
            int cc = (n0 & 255) + j * 16 + lr;
            int hh = cc >> 5, dk = cc & 31;
            int rl = w * 32 + i * 16 + lg * 4;
            size_t ho = ((size_t)(nn * HH + hh) * LL + rl) * DK + dk;
#pragma unroll
            for (int q = 0; q < 4; ++q)
                dst[ho + (size_t)q * DK] = acc[i][j][q];
        }
}

// ---------------------------------------------------------------------------
// Fused sparse attention v7: only the 6 kNN columns per row survive the
// softmax (masked cols give exp(-1e9-mx)=0 exactly in f32), so compute
// scores/softmax/PV over just those 6. One thread per (bh, row).
// ---------------------------------------------------------------------------
__global__ __launch_bounds__(256)
void fattn7(const float* __restrict__ qh, const float* __restrict__ kh,
            const float* __restrict__ vh, const float* __restrict__ cost,
            const unsigned long long* __restrict__ idx8,
            const float* __restrict__ m1w, const float* __restrict__ m1b,
            const float* __restrict__ m2w, const float* __restrict__ m2b,
            unsigned short* __restrict__ attc) {
    int t = blockIdx.x * 256 + threadIdx.x;
    int bh = t >> 7, r = t & 127;
    int n = bh >> 3, hh = bh & 7;
    int hu = __builtin_amdgcn_readfirstlane(hh);   // wave-uniform
    const float* w0g = m1w + (hu * 2 + 0) * MS;
    const float* w1g = m1w + (hu * 2 + 1) * MS;
    const float* b1g = m1b + hu * MS;
    const float* w2g = m2w + hu * MS;
    float b2v = m2b[hu];
    const float scale = 0.17677669529663687f;   // 1/sqrt(32)

    const float4* qr = reinterpret_cast<const float4*>(qh + ((size_t)bh * LL + r) * DK);
    float4 q[8];
#pragma unroll
    for (int j = 0; j < 8; ++j) q[j] = qr[j];

    unsigned long long pk = idx8[(size_t)n * LL + r];
    const float* kbase = kh + (size_t)bh * LL * DK;
    const float* vbase = vh + (size_t)bh * LL * DK;
    const float* crow = cost + ((size_t)n * LL + r) * LL;

    int col[KNN];
#pragma unroll
    for (int k = 0; k < KNN; ++k) col[k] = (int)((pk >> (k * 8)) & 0xFF);

    float e[KNN];
    float mx = -3.4e38f;
#pragma unroll
    for (int k = 0; k < KNN; ++k) {
        const float4* kr = reinterpret_cast<const float4*>(kbase + (size_t)col[k] * DK);
        float d = 0.f;
#pragma unroll
        for (int j = 0; j < 8; ++j) {
            float4 kv = kr[j];
            d += q[j].x * kv.x + q[j].y * kv.y + q[j].z * kv.z + q[j].w * kv.w;
        }
        d *= scale;
        float cst = crow[col[k]];
        float s = b2v;
#pragma unroll
        for (int m = 0; m < MS; ++m)
            s += fmaxf(d * w0g[m] + cst * w1g[m] + b1g[m], 0.f) * w2g[m];
        e[k] = s;
        mx = fmaxf(mx, s);
    }
    float sum = 0.f;
#pragma unroll
    for (int k = 0; k < KNN; ++k) { e[k] = __expf(e[k] - mx); sum += e[k]; }
    float inv = 1.f / sum;

    float4 att[8];
#pragma unroll
    for (int j = 0; j < 8; ++j) att[j] = make_float4(0.f, 0.f, 0.f, 0.f);
#pragma unroll
    for (int k = 0; k < KNN; ++k) {
        float wgt = e[k] * inv;
        const float4* vr = reinterpret_cast<const float4*>(vbase + (size_t)col[k] * DK);
#pragma unroll
        for (int j = 0; j < 8; ++j) {
            float4 vv = vr[j];
            att[j].x += wgt * vv.x; att[j].y += wgt * vv.y;
            att[j].z += wgt * vv.z; att[j].w += wgt * vv.w;
        }
    }
    unsigned short* dst = attc + ((size_t)(n * LL + r)) * DD + hh * DK;
#pragma unroll
    for (int j = 0; j < 8; ++j) {
        ushort4 u;
        u.x = f2b(att[j].x); u.y = f2b(att[j].y);
        u.z = f2b(att[j].z); u.w = f2b(att[j].w);
        *reinterpret_cast<ushort4*>(dst + j * 4) = u;
    }
}

// ---------------------------------------------------------------------------
// out = LayerNorm(a + b) * g + be ; wave-per-row, no barriers.
// ---------------------------------------------------------------------------
__global__ __launch_bounds__(256)
void add_ln2(const float* __restrict__ a, const float* __restrict__ b,
             const float* __restrict__ g, const float* __restrict__ be,
             float* __restrict__ out, unsigned short* __restrict__ outb) {
    int m = blockIdx.x * 4 + (threadIdx.x >> 6);
    int l = threadIdx.x & 63;
    size_t off = (size_t)m * DD + l * 4;
    float4 av = *reinterpret_cast<const float4*>(a + off);
    float4 bv = *reinterpret_cast<const float4*>(b + off);
    float4 x = make_float4(av.x + bv.x, av.y + bv.y, av.z + bv.z, av.w + bv.w);
    float s = x.x + x.y + x.z + x.w;
#pragma unroll
    for (int o = 1; o < 64; o <<= 1) s += __shfl_xor(s, o);
    float mean = s * (1.0f / 256.0f);
    float4 d = make_float4(x.x - mean, x.y - mean, x.z - mean, x.w - mean);
    float s2 = d.x * d.x + d.y * d.y + d.z * d.z + d.w * d.w;
#pragma unroll
    for (int o = 1; o < 64; o <<= 1) s2 += __shfl_xor(s2, o);
    float inv = 1.f / sqrtf(s2 * (1.0f / 256.0f) + 1e-5f);
    float4 gv = *reinterpret_cast<const float4*>(g + l * 4);
    float4 ev = *reinterpret_cast<const float4*>(be + l * 4);
    float4 r = make_float4(d.x * inv * gv.x + ev.x, d.y * inv * gv.y + ev.y,
                           d.z * inv * gv.z + ev.z, d.w * inv * gv.w + ev.w);
    *reinterpret_cast<float4*>(out + off) = r;
    ushort4 u; u.x = f2b(r.x); u.y = f2b(r.y); u.z = f2b(r.z); u.w = f2b(r.w);
    *reinterpret_cast<ushort4*>(outb + off) = u;
}

// ---------------------------------------------------------------------------
extern "C" void kernel_launch(void* const* d_in, const int* in_sizes, int n_in,
                              void* d_out, int out_size, void* d_ws, size_t ws_size,
                              hipStream_t stream) {
    const float* vehicles = (const float*)d_in[0];
    const float* fleet    = (const float*)d_in[1];
    const float* Wproj    = (const float*)d_in[2];
    const float* bproj    = (const float*)d_in[3];
    const float* Wq       = (const float*)d_in[4];
    const float* Wk       = (const float*)d_in[5];
    const float* Wv       = (const float*)d_in[6];
    const float* m1w      = (const float*)d_in[7];
    const float* m1b      = (const float*)d_in[8];
    const float* m2w      = (const float*)d_in[9];
    const float* m2b      = (const float*)d_in[10];
    const float* Wo       = (const float*)d_in[11];
    const float* bo       = (const float*)d_in[12];
    const float* n1_g     = (const float*)d_in[13];
    const float* n1_b     = (const float*)d_in[14];
    const float* ff1_w    = (const float*)d_in[15];
    const float* ff1_b    = (const float*)d_in[16];
    const float* ff2_w    = (const float*)d_in[17];
    const float* ff2_b    = (const float*)d_in[18];
    const float* n2_g     = (const float*)d_in[19];
    const float* n2_b     = (const float*)d_in[20];

    const size_t MROWS = (size_t)NB * LL;           // 8192
    const size_t HSZ   = MROWS * DD;                // 2,097,152

    float* ws = (float*)d_ws;
    float* h    = ws;                                // HSZ f32
    float* tmp  = h + HSZ;                           // HSZ f32
    float* cost = tmp + HSZ;                         // 1,048,576 f32
    float* qh   = cost + 1048576;                    // HSZ f32
    float* kh   = qh + HSZ;                          // HSZ f32
    float* vh   = kh + HSZ;                          // HSZ f32
    unsigned short* hb    = (unsigned short*)(vh + HSZ);            // HSZ bf16
    unsigned short* attc  = hb + HSZ;                               // HSZ bf16
    unsigned short* ffmid = attc + HSZ;                             // M*FF bf16
    unsigned short* Wt    = ffmid + MROWS * FF;                     // 3*WLS bf16
    unsigned long long* idx8 = (unsigned long long*)(Wt + 3 * WLS); // 8192 u64

    // preprocessing
    pack_cost<<<1024, 256, 0, stream>>>(fleet, cost);
    proj2<<<2048, 256, 0, stream>>>(vehicles, Wproj, bproj, h, hb);
    knn_idx<<<2048, 256, 0, stream>>>(cost, idx8);

    transposeW4<<<dim3(8, 8, 12), 256, 0, stream>>>(Wq, Wk, Wv, Wo, Wt);
    transposeW<<<dim3(32, 8, 3), 256, 0, stream>>>(ff1_w, Wt + 262144, DD, FF, DD * FF, WLS);
    transposeW<<<dim3(8, 32, 3), 256, 0, stream>>>(ff2_w, Wt + 524288, FF, DD, FF * DD, WLS);

    dim3 gqkv(12, 64);   // qkv3: N=768, 128x64 tiles
    dim3 g256(4, 64);    // mmfma128: N=256
    dim3 gff1(8, 64);    // mmfma256relu: N=1024, 128x128 tiles

    for (int i = 0; i < LC; ++i) {
        const unsigned short* wt = Wt + (size_t)i * WLS;

        qkv3<<<gqkv, 256, 0, stream>>>(hb, wt, qh, kh, vh);

        fattn7<<<256, 256, 0, stream>>>(
            qh, kh, vh, cost, idx8,
            m1w + (size_t)i * HH * 2 * MS, m1b + (size_t)i * HH * MS,
            m2w + (size_t)i * HH * MS,     m2b + (size_t)i * HH,
            attc);

        mmfma128<0><<<g256, 256, 0, stream>>>(attc, wt + 196608, bo + (size_t)i * DD,
                                              tmp, (int)MROWS, DD, DD);
        add_ln2<<<2048, 256, 0, stream>>>(h, tmp, n1_g + (size_t)i * DD,
                                          n1_b + (size_t)i * DD, h, hb);

        mmfma256relu<<<gff1, 256, 0, stream>>>(hb, wt + 262144, ff1_b + (size_t)i * FF,
                                               ffmid, (int)MROWS, FF, DD);
        mmfma128<0><<<g256, 256, 0, stream>>>(ffmid, wt + 524288, ff2_b + (size_t)i * DD,
                                              tmp, (int)MROWS, DD, FF);

        float* dst = (i == LC - 1) ? (float*)d_out : h;
        add_ln2<<<2048, 256, 0, stream>>>(h, tmp, n2_g + (size_t)i * DD,
                                          n2_b + (size_t)i * DD, dst, hb);
    }
}